// Round 20
// baseline (246.395 us; speedup 1.0000x reference)
//
#include <hip/hip_runtime.h>
#include <hip/hip_bf16.h>

// ---------------------------------------------------------------------------
// MultiHeadAttention: x[2,2048,2048] f32, W_qkv[6144,2048], W_out[2048,2048]
// out = MHA(x) in fp32. Internally bf16 MFMA with fp32 accumulation.
// ---------------------------------------------------------------------------

typedef short bf16x8 __attribute__((ext_vector_type(8)));
typedef float f32x4  __attribute__((ext_vector_type(4)));

#define MFMA(a, b, c) __builtin_amdgcn_mfma_f32_16x16x32_bf16((a), (b), (c), 0, 0, 0)

#define GLDS16(gp, lp) __builtin_amdgcn_global_load_lds(                        \
    (const __attribute__((address_space(1))) void*)(gp),                        \
    (__attribute__((address_space(3))) void*)(lp), 16, 0, 0)

static __device__ __forceinline__ unsigned short f2bf(float f) {
    __hip_bfloat16 h = __float2bfloat16(f);
    return *reinterpret_cast<unsigned short*>(&h);
}

// ---------------- fp32 -> bf16 convert (fused, grid-stride over 3 arrays) ---
__global__ __launch_bounds__(256) void cvt3_f32_bf16(const float* __restrict__ x,
                                                     const float* __restrict__ wq,
                                                     const float* __restrict__ wo,
                                                     unsigned short* __restrict__ xb,
                                                     unsigned short* __restrict__ wqb,
                                                     unsigned short* __restrict__ wob) {
    // region sizes in float4 units: x 2097152, wq 3145728, wo 1048576
    const int i = blockIdx.x * 256 + threadIdx.x;   // grid covers 6291456
    const float* src; unsigned short* dst; int k;
    if (i < 2097152)      { src = x;  dst = xb;  k = i; }
    else if (i < 5242880) { src = wq; dst = wqb; k = i - 2097152; }
    else                  { src = wo; dst = wob; k = i - 5242880; }
    float4 v = reinterpret_cast<const float4*>(src)[k];
    ushort4 o;
    o.x = f2bf(v.x); o.y = f2bf(v.y); o.z = f2bf(v.z); o.w = f2bf(v.w);
    reinterpret_cast<ushort4*>(dst)[k] = o;
}

// ---------------- QKV GEMM: 256x128 tile, BK=64, 8 waves (R19->R20) ---------
// R15's verified K-loop/swizzle with BM=256: grid 16x48 = 768 blocks = EXACTLY
// 3/CU (48KB LDS, 1536 threads) -> zero dispatch tail (1.0 rounds vs 1.2);
// staging/thread 8 -> 6 gload_lds (B-panel feeds 2x M-rows, B-traffic halves);
// 24 waves/CU (6/SIMD) hides the per-iter drain better. Per-wave inner loop,
// swizzle (byte ^= ((row&7)<<4), inverse-swizzled source, rule #21), register
// pressure, and K summation order are IDENTICAL to gemm_bt64.
__global__ __launch_bounds__(512) void gemm_qkv256(const unsigned short* __restrict__ A,
                                                   const unsigned short* __restrict__ W,
                                                   unsigned short* __restrict__ Cout,
                                                   int M, int N, int K) {
    __shared__ unsigned short As[256 * 64];   // 32KB, swizzled layout
    __shared__ unsigned short Bs[128 * 64];   // 16KB
    const int tid = threadIdx.x;
    const int w = tid >> 6, lane = tid & 63;   // w 0..7
    const int fr = lane & 15, fq = lane >> 4;
    const int m0 = blockIdx.y * 256, n0 = blockIdx.x * 128;
    const int wr = w >> 1, wc = w & 1;         // 4M x 2N waves of 64x64

    f32x4 acc[4][4];
#pragma unroll
    for (int a = 0; a < 4; a++)
#pragma unroll
        for (int b = 0; b < 4; b++) acc[a][b] = f32x4{0.f, 0.f, 0.f, 0.f};

    const int srow = lane >> 3;
    const int sce  = ((lane & 7) ^ (lane >> 3)) * 8;   // elems (inv-swizzle)

    for (int kt = 0; kt < K; kt += 64) {
        __syncthreads();
        // A: 32 x 1KB instrs (rows 8i..8i+7), wave w does i = w*4..w*4+3
#pragma unroll
        for (int q = 0; q < 4; ++q) {
            const int i = w * 4 + q;               // 0..31
            const int r = i * 8 + srow;            // 0..255
            GLDS16(A + (size_t)(m0 + r) * K + kt + sce, As + i * 512);
        }
        // B: 16 x 1KB instrs, wave w does i = w*2..w*2+1
#pragma unroll
        for (int q = 0; q < 2; ++q) {
            const int i = w * 2 + q;               // 0..15
            const int r = i * 8 + srow;            // 0..127
            GLDS16(W + (size_t)(n0 + r) * K + kt + sce, Bs + i * 512);
        }
        asm volatile("s_waitcnt vmcnt(0)" ::: "memory");
        __syncthreads();

#pragma unroll
        for (int kk = 0; kk < 2; ++kk) {
            bf16x8 af[4], bfr[4];
#pragma unroll
            for (int mi = 0; mi < 4; mi++) {
                const int row = wr * 64 + mi * 16 + fr;   // 0..255
                af[mi] = *reinterpret_cast<const bf16x8*>(
                    As + row * 64 + ((((kk * 64 + fq * 16) ^ ((fr & 7) << 4))) >> 1));
            }
#pragma unroll
            for (int ni = 0; ni < 4; ni++) {
                const int row = wc * 64 + ni * 16 + fr;   // 0..127
                bfr[ni] = *reinterpret_cast<const bf16x8*>(
                    Bs + row * 64 + ((((kk * 64 + fq * 16) ^ ((fr & 7) << 4))) >> 1));
            }
            __builtin_amdgcn_s_setprio(1);
#pragma unroll
            for (int mi = 0; mi < 4; mi++)
#pragma unroll
                for (int ni = 0; ni < 4; ni++)
                    acc[mi][ni] = MFMA(af[mi], bfr[ni], acc[mi][ni]);
            __builtin_amdgcn_s_setprio(0);
        }
    }

    // epilogue: C/D layout col=lane&15, row=(lane>>4)*4+reg  [verified m89/m91]
#pragma unroll
    for (int mi = 0; mi < 4; mi++) {
#pragma unroll
        for (int i = 0; i < 4; i++) {
            const int row = m0 + wr * 64 + mi * 16 + fq * 4 + i;
            const size_t base = (size_t)row * N + n0 + wc * 64 + fr;
#pragma unroll
            for (int ni = 0; ni < 4; ni++)
                Cout[base + ni * 16] = f2bf(acc[mi][ni][i]);
        }
    }
}

// ---------------- GEMM (double-buffer): BK=64 + XOR swizzle [R16] -----------
// stage(t+1 -> buf^1) at iter top, ONE __syncthreads per iter whose implicit
// drain lands AFTER compute. 64KB LDS caps 2 blocks/CU -- used ONLY where the
// grid is already <= 2 blocks/CU (out-GEMM: 512 blocks), so drain-hiding is
// free (R16/R17 A/B).
template <bool BF16OUT>
__global__ __launch_bounds__(256) void gemm_bt64_db(const unsigned short* __restrict__ A,
                                                    const unsigned short* __restrict__ W,
                                                    void* __restrict__ Cout,
                                                    int M, int N, int K) {
    __shared__ unsigned short As[2][128 * 64];   // 2 x 16KB, swizzled layout
    __shared__ unsigned short Bs[2][128 * 64];
    const int tid = threadIdx.x;
    const int w = tid >> 6, lane = tid & 63;
    const int fr = lane & 15, fq = lane >> 4;
    const int m0 = blockIdx.y * 128, n0 = blockIdx.x * 128;
    const int wr = w >> 1, wc = w & 1;

    f32x4 acc[4][4];
#pragma unroll
    for (int a = 0; a < 4; a++)
#pragma unroll
        for (int b = 0; b < 4; b++) acc[a][b] = f32x4{0.f, 0.f, 0.f, 0.f};

    const int srow = lane >> 3;
    const int sce  = ((lane & 7) ^ (lane >> 3)) * 8;   // elems (inv-swizzle)

    auto stage = [&](int kt, int bufi) {
#pragma unroll
        for (int q = 0; q < 4; ++q) {
            const int i = w * 4 + q;               // 0..15
            const int r = i * 8 + srow;            // 0..127
            GLDS16(A + (size_t)(m0 + r) * K + kt + sce, &As[bufi][i * 512]);
            GLDS16(W + (size_t)(n0 + r) * K + kt + sce, &Bs[bufi][i * 512]);
        }
    };

    const int NT = K >> 6;   // 64-wide K-tiles
    int cur = 0;
    stage(0, 0);
    __syncthreads();         // compiler drains vmcnt before s_barrier

    for (int it = 0; it < NT; ++it) {
        if (it + 1 < NT) stage((it + 1) << 6, cur ^ 1);   // issue-early
#pragma unroll
        for (int kk = 0; kk < 2; ++kk) {
            bf16x8 af[4], bfr[4];
#pragma unroll
            for (int mi = 0; mi < 4; mi++) {
                const int row = wr * 64 + mi * 16 + fr;
                af[mi] = *reinterpret_cast<const bf16x8*>(
                    &As[cur][0] + row * 64 + ((((kk * 64 + fq * 16) ^ ((fr & 7) << 4))) >> 1));
            }
#pragma unroll
            for (int ni = 0; ni < 4; ni++) {
                const int row = wc * 64 + ni * 16 + fr;
                bfr[ni] = *reinterpret_cast<const bf16x8*>(
                    &Bs[cur][0] + row * 64 + ((((kk * 64 + fq * 16) ^ ((fr & 7) << 4))) >> 1));
            }
            __builtin_amdgcn_s_setprio(1);
#pragma unroll
            for (int mi = 0; mi < 4; mi++)
#pragma unroll
                for (int ni = 0; ni < 4; ni++)
                    acc[mi][ni] = MFMA(af[mi], bfr[ni], acc[mi][ni]);
            __builtin_amdgcn_s_setprio(0);
        }
        __syncthreads();     // drains staging (after compute) + orders reuse
        cur ^= 1;
    }

    // epilogue: C/D layout col=lane&15, row=(lane>>4)*4+reg  [verified m89/m91]
#pragma unroll
    for (int mi = 0; mi < 4; mi++) {
#pragma unroll
        for (int i = 0; i < 4; i++) {
            const int row = m0 + wr * 64 + mi * 16 + fq * 4 + i;
            const size_t base = (size_t)row * N + n0 + wc * 64 + fr;
#pragma unroll
            for (int ni = 0; ni < 4; ni++) {
                if (BF16OUT)
                    ((unsigned short*)Cout)[base + ni * 16] = f2bf(acc[mi][ni][i]);
                else
                    ((float*)Cout)[base + ni * 16] = acc[mi][ni][i];
            }
        }
    }
}

// ---------------- V transpose: qkv V-part [4096][2048] -> vT[2][2048][2048] --
__global__ __launch_bounds__(256) void transpose_v(const unsigned short* __restrict__ qkv,
                                                   unsigned short* __restrict__ vT) {
    __shared__ unsigned short t[32][33];
    const int b = blockIdx.z, ts = blockIdx.x, tu = blockIdx.y;
    const int i = threadIdx.x >> 5, j = threadIdx.x & 31;
#pragma unroll
    for (int ii = 0; ii < 4; ++ii) {
        const int row = i + ii * 8;
        t[row][j] = qkv[(size_t)(b * 2048 + ts * 32 + row) * 6144 + 4096 + tu * 32 + j];
    }
    __syncthreads();
#pragma unroll
    for (int ii = 0; ii < 4; ++ii) {
        const int row = i + ii * 8;
        vT[(size_t)(b * 2048 + tu * 32 + row) * 2048 + ts * 32 + j] = t[j][row];
    }
}

// ---------------- Flash attention, causal, block-cooperative, KVBLK=64 ------
// R10 configuration (best known): 512 blocks, each = one (b,h) x TWO 64-row
// q-supertiles {g=31-j, g=j} -> exactly 33 kv-iterations per block (perfect
// balance, 2 blocks/CU). Per kv-iter: stage K[64][128]+Vt[128][64] (32KB)
// into double-buffered LDS via global_load_lds (pre-swizzled source,
// XOR-swizzled reads, byte ^= ((row&7)<<4)). Fixed-reference exp2 softmax
// (no max-reduce), denominator on the MFMA pipe via ones-B.
#define SC2 (0.08838834764831845f * 1.4426950408889634f)  // SM_SCALE*log2(e)
#define MREF 20.0f

__global__ __launch_bounds__(256, 2) void attn_fwd(const unsigned short* __restrict__ qkv,
                                                   const unsigned short* __restrict__ vT,
                                                   unsigned short* __restrict__ ao) {
    __shared__ __align__(16) char Kt[2][16384];   // 64 rows x 256B
    __shared__ __align__(16) char Vt[2][16384];   // 128 rows x 128B
    __shared__ __align__(16) unsigned short Ps[4][16 * 72];  // 16 x 64, stride 72
    const int tid = threadIdx.x;
    const int w = tid >> 6, lane = tid & 63;
    const int fr = lane & 15, fq = lane >> 4;
    const int t = blockIdx.x;           // 512 blocks
    const int bh = t & 31;              // bh%8 ~ XCD id: 4 heads per XCD L2
    const int j = t >> 5;               // 0..15 -> pair {31-j, j}
    const int b = bh >> 4, h = bh & 15;

    const unsigned short* Qb = qkv + (size_t)b * 2048 * 6144 + h * 128;
    const unsigned short* Kb = qkv + (size_t)b * 2048 * 6144 + (16 + h) * 128;
    const unsigned short* Vb = vT + (size_t)bh * 128 * 2048;

    unsigned short* Pw = &Ps[w][0];
    const bf16x8 onesf = {0x3F80, 0x3F80, 0x3F80, 0x3F80, 0x3F80, 0x3F80, 0x3F80, 0x3F80};

    // staging: waves 0,1 -> K (16 x 1KB instr), waves 2,3 -> Vt (16 x 1KB).
    auto stage = [&](int kbs, int bufi) {
        const int k0s = kbs * 64;
        if (w < 2) {
#pragma unroll
            for (int q = 0; q < 8; ++q) {
                const int i = w * 8 + q;
                const int r = 4 * i + (lane >> 4);
                const int ce = ((((lane & 15) * 16) ^ ((r & 7) << 4))) >> 1;
                GLDS16(Kb + (size_t)(k0s + r) * 6144 + ce, &Kt[bufi][i * 1024]);
            }
        } else {
#pragma unroll
            for (int q = 0; q < 8; ++q) {
                const int i = (w - 2) * 8 + q;
                const int r = 8 * i + (lane >> 3);
                const int ce = ((lane & 7) ^ ((lane >> 3) & 7)) * 8;
                GLDS16(Vb + (size_t)r * 2048 + k0s + ce, &Vt[bufi][i * 1024]);
            }
        }
    };

#pragma unroll 1
    for (int seg = 0; seg < 2; ++seg) {
        const int g = seg ? j : 31 - j;   // heavy supertile first
        const int q0 = g * 64 + w * 16;
        const int nb = g + 1;

        bf16x8 qf[4];
        {
            const unsigned short* qr = Qb + (size_t)(q0 + fr) * 6144 + fq * 8;
#pragma unroll
            for (int c = 0; c < 4; c++) qf[c] = *reinterpret_cast<const bf16x8*>(qr + c * 32);
        }

        f32x4 acc[8];
#pragma unroll
        for (int f = 0; f < 8; f++) acc[f] = f32x4{0.f, 0.f, 0.f, 0.f};
        f32x4 accL = f32x4{0.f, 0.f, 0.f, 0.f};   // row-sum of P (denominator)

        int cur = 0;
        stage(0, 0);
        __syncthreads();

        for (int kb = 0; kb < nb; ++kb) {
            if (kb + 1 < nb) stage(kb + 1, cur ^ 1);
            const int k0 = kb * 64;
            const char* Kl = &Kt[cur][0];
            const char* Vl = &Vt[cur][0];

            // ---- QK^T: 4 16-col score tiles, two register-reusing halves ----
            f32x4 s[4];
#pragma unroll
            for (int th = 0; th < 2; ++th) {
                bf16x8 kf[2][4];
#pragma unroll
                for (int t2 = 0; t2 < 2; ++t2) {
                    const int tt = th * 2 + t2;
#pragma unroll
                    for (int c = 0; c < 4; ++c)
                        kf[t2][c] = *reinterpret_cast<const bf16x8*>(
                            Kl + (tt * 16 + fr) * 256 + ((c * 64 + fq * 16) ^ ((fr & 7) << 4)));
                }
                f32x4 a0 = f32x4{0.f, 0.f, 0.f, 0.f}, a1 = f32x4{0.f, 0.f, 0.f, 0.f};
                __builtin_amdgcn_s_setprio(1);
#pragma unroll
                for (int c = 0; c < 4; ++c) {
                    a0 = MFMA(qf[c], kf[0][c], a0);
                    a1 = MFMA(qf[c], kf[1][c], a1);
                }
                __builtin_amdgcn_s_setprio(0);
                s[th * 2] = a0; s[th * 2 + 1] = a1;
            }

            // ---- fixed-reference softmax: P = 2^(s*SC2 - MREF), no reduce ----
            const bool diag = (kb == nb - 1);   // wave-uniform
#pragma unroll
            for (int i = 0; i < 4; ++i) {
                const int qrow = q0 + fq * 4 + i;
#pragma unroll
                for (int tt = 0; tt < 4; ++tt) {
                    float a = __builtin_fmaf(s[tt][i], SC2, -MREF);
                    if (diag && (k0 + tt * 16 + fr > qrow)) a = -__builtin_inff();
                    Pw[(fq * 4 + i) * 72 + tt * 16 + fr] = f2bf(exp2f(a));
                }
            }

            // ---- PV + row-sum: two kv-halves of 32, register-reusing vf ----
#pragma unroll
            for (int h2 = 0; h2 < 2; ++h2) {
                bf16x8 pa = *reinterpret_cast<const bf16x8*>(Pw + fr * 72 + h2 * 32 + fq * 8);
                bf16x8 vf[8];
#pragma unroll
                for (int f = 0; f < 8; ++f)
                    vf[f] = *reinterpret_cast<const bf16x8*>(
                        Vl + (f * 16 + fr) * 128 + ((h2 * 64 + fq * 16) ^ ((fr & 7) << 4)));
                __builtin_amdgcn_s_setprio(1);
#pragma unroll
                for (int f = 0; f < 8; ++f) acc[f] = MFMA(pa, vf[f], acc[f]);
                accL = MFMA(pa, onesf, accL);   // denominator on the MFMA pipe
                __builtin_amdgcn_s_setprio(0);
            }

            __syncthreads();
            cur ^= 1;
        }

        // epilogue: normalize (reciprocal-multiply) and store bf16 [4096][2048]
        float inv[4];
#pragma unroll
        for (int i = 0; i < 4; ++i) inv[i] = 1.0f / accL[i];
#pragma unroll
        for (int f = 0; f < 8; f++) {
#pragma unroll
            for (int i = 0; i < 4; i++) {
                const int qrow = q0 + fq * 4 + i;
                const float o = acc[f][i] * inv[i];
                ao[(size_t)(b * 2048 + qrow) * 2048 + h * 128 + f * 16 + fr] = f2bf(o);
            }
        }
        // all waves passed the loop's final barrier; epilogue touches no LDS,
        // so seg1's stage(0,0) can safely overwrite buffers.
    }
}

// ---------------------------------------------------------------------------
extern "C" void kernel_launch(void* const* d_in, const int* in_sizes, int n_in,
                              void* d_out, int out_size, void* d_ws, size_t ws_size,
                              hipStream_t stream) {
    const float* x    = (const float*)d_in[0];
    const float* Wqkv = (const float*)d_in[1];
    const float* Wout = (const float*)d_in[2];
    float* out = (float*)d_out;

    // Workspace layout (96 MB), regions reused across phases:
    //   [0,16M):   xb (bf16 x), later reused as attnb
    //   [16M,40M): wqkvb (24M), later reused as vT (16M)
    //   [40M,48M): woutb
    //   [48M,96M): qkvb (bf16 [4096][6144])
    char* ws = (char*)d_ws;
    unsigned short* xb    = (unsigned short*)(ws);
    unsigned short* wqkvb = (unsigned short*)(ws + (size_t)(16 << 20));
    unsigned short* woutb = (unsigned short*)(ws + (size_t)(40 << 20));
    unsigned short* qkvb  = (unsigned short*)(ws + (size_t)(48 << 20));
    unsigned short* vTb   = (unsigned short*)(ws + (size_t)(16 << 20)); // over wqkvb
    unsigned short* attnb = (unsigned short*)(ws);                      // over xb

    // fused fp32->bf16 convert of x, W_qkv, W_out (one dispatch)
    cvt3_f32_bf16<<<24576, 256, 0, stream>>>(x, Wqkv, Wout, xb, wqkvb, woutb);

    // qkv = x @ W_qkv^T : M=4096, N=6144, K=2048, bf16 out
    // 256x128 tile, 768 blocks = exactly 3/CU (zero tail), BK=64 swizzled
    gemm_qkv256<<<dim3(48, 16), 512, 0, stream>>>(xb, wqkvb, qkvb, 4096, 6144, 2048);

    // vT[b][h*128+dk][s] = V[b][s][h*128+dk]  (wqkvb dead after the GEMM)
    transpose_v<<<dim3(64, 64, 2), 256, 0, stream>>>(qkvb, vTb);

    // causal flash attention -> attnb (bf16 [4096][2048])  (xb dead now)
    attn_fwd<<<512, 256, 0, stream>>>(qkvb, vTb, attnb);

    // out = attnb @ W_out^T : M=4096, N=2048, K=2048, fp32 out
    // double-buffer BK=64 (512 blocks = 2/CU by grid -> dbuf free, R16 A/B)
    gemm_bt64_db<false><<<dim3(16, 32), 256, 0, stream>>>(attnb, woutb, out, 4096, 2048, 2048);
}

// Round 21
// 241.991 us; speedup vs baseline: 1.0182x; 1.0182x over previous
//
#include <hip/hip_runtime.h>
#include <hip/hip_bf16.h>

// ---------------------------------------------------------------------------
// MultiHeadAttention: x[2,2048,2048] f32, W_qkv[6144,2048], W_out[2048,2048]
// out = MHA(x) in fp32. Internally bf16 MFMA with fp32 accumulation.
// Session-best configuration (R17, 242.2us): QKV = single-buffer BK=64
// swizzled GEMM; out = double-buffer BK=64 (grid-capped at 2/CU so dbuf is
// free); attn = R10 block-cooperative KVBLK=64, fixed-reference exp2 softmax.
// ---------------------------------------------------------------------------

typedef short bf16x8 __attribute__((ext_vector_type(8)));
typedef float f32x4  __attribute__((ext_vector_type(4)));

#define MFMA(a, b, c) __builtin_amdgcn_mfma_f32_16x16x32_bf16((a), (b), (c), 0, 0, 0)

#define GLDS16(gp, lp) __builtin_amdgcn_global_load_lds(                        \
    (const __attribute__((address_space(1))) void*)(gp),                        \
    (__attribute__((address_space(3))) void*)(lp), 16, 0, 0)

static __device__ __forceinline__ unsigned short f2bf(float f) {
    __hip_bfloat16 h = __float2bfloat16(f);
    return *reinterpret_cast<unsigned short*>(&h);
}

// ---------------- fp32 -> bf16 convert (fused, grid-stride over 3 arrays) ---
__global__ __launch_bounds__(256) void cvt3_f32_bf16(const float* __restrict__ x,
                                                     const float* __restrict__ wq,
                                                     const float* __restrict__ wo,
                                                     unsigned short* __restrict__ xb,
                                                     unsigned short* __restrict__ wqb,
                                                     unsigned short* __restrict__ wob) {
    // region sizes in float4 units: x 2097152, wq 3145728, wo 1048576
    const int i = blockIdx.x * 256 + threadIdx.x;   // grid covers 6291456
    const float* src; unsigned short* dst; int k;
    if (i < 2097152)      { src = x;  dst = xb;  k = i; }
    else if (i < 5242880) { src = wq; dst = wqb; k = i - 2097152; }
    else                  { src = wo; dst = wob; k = i - 5242880; }
    float4 v = reinterpret_cast<const float4*>(src)[k];
    ushort4 o;
    o.x = f2bf(v.x); o.y = f2bf(v.y); o.z = f2bf(v.z); o.w = f2bf(v.w);
    reinterpret_cast<ushort4*>(dst)[k] = o;
}

// ---------------- GEMM (single-buffer): BK=64 + XOR swizzle [R15: 105us] ----
// m97 wave layout, BK=64 halves per-iter vmcnt+barrier fixed cost. 32KB LDS
// keeps ~2.4 blocks/CU (occupancy beats dbuf's drain-hiding here -- R16 A/B).
// Both-sides XOR swizzle (byte ^= ((row&7)<<4)): linear global_load_lds dest
// + inverse-swizzled global source (rule #21); bank conflicts measured 0.
template <bool BF16OUT>
__global__ __launch_bounds__(256) void gemm_bt64(const unsigned short* __restrict__ A,
                                                 const unsigned short* __restrict__ W,
                                                 void* __restrict__ Cout,
                                                 int M, int N, int K) {
    __shared__ unsigned short As[128 * 64];   // 16KB, swizzled layout
    __shared__ unsigned short Bs[128 * 64];
    const int tid = threadIdx.x;
    const int w = tid >> 6, lane = tid & 63;
    const int fr = lane & 15, fq = lane >> 4;
    const int m0 = blockIdx.y * 128, n0 = blockIdx.x * 128;
    const int wr = w >> 1, wc = w & 1;

    f32x4 acc[4][4];
#pragma unroll
    for (int a = 0; a < 4; a++)
#pragma unroll
        for (int b = 0; b < 4; b++) acc[a][b] = f32x4{0.f, 0.f, 0.f, 0.f};

    const int srow = lane >> 3;
    const int sce  = ((lane & 7) ^ (lane >> 3)) * 8;   // elems (inv-swizzle)

    for (int kt = 0; kt < K; kt += 64) {
        __syncthreads();
#pragma unroll
        for (int q = 0; q < 4; ++q) {
            const int i = w * 4 + q;               // 0..15
            const int r = i * 8 + srow;            // 0..127
            GLDS16(A + (size_t)(m0 + r) * K + kt + sce, As + i * 512);
            GLDS16(W + (size_t)(n0 + r) * K + kt + sce, Bs + i * 512);
        }
        asm volatile("s_waitcnt vmcnt(0)" ::: "memory");
        __syncthreads();

#pragma unroll
        for (int kk = 0; kk < 2; ++kk) {
            bf16x8 af[4], bfr[4];
#pragma unroll
            for (int mi = 0; mi < 4; mi++) {
                const int row = wr * 64 + mi * 16 + fr;
                af[mi] = *reinterpret_cast<const bf16x8*>(
                    As + row * 64 + ((((kk * 64 + fq * 16) ^ ((fr & 7) << 4))) >> 1));
            }
#pragma unroll
            for (int ni = 0; ni < 4; ni++) {
                const int row = wc * 64 + ni * 16 + fr;
                bfr[ni] = *reinterpret_cast<const bf16x8*>(
                    Bs + row * 64 + ((((kk * 64 + fq * 16) ^ ((fr & 7) << 4))) >> 1));
            }
            __builtin_amdgcn_s_setprio(1);
#pragma unroll
            for (int mi = 0; mi < 4; mi++)
#pragma unroll
                for (int ni = 0; ni < 4; ni++)
                    acc[mi][ni] = MFMA(af[mi], bfr[ni], acc[mi][ni]);
            __builtin_amdgcn_s_setprio(0);
        }
    }

    // epilogue: C/D layout col=lane&15, row=(lane>>4)*4+reg  [verified m89/m91]
#pragma unroll
    for (int mi = 0; mi < 4; mi++) {
#pragma unroll
        for (int i = 0; i < 4; i++) {
            const int row = m0 + wr * 64 + mi * 16 + fq * 4 + i;
            const size_t base = (size_t)row * N + n0 + wc * 64 + fr;
#pragma unroll
            for (int ni = 0; ni < 4; ni++) {
                if (BF16OUT)
                    ((unsigned short*)Cout)[base + ni * 16] = f2bf(acc[mi][ni][i]);
                else
                    ((float*)Cout)[base + ni * 16] = acc[mi][ni][i];
            }
        }
    }
}

// ---------------- GEMM (double-buffer): BK=64 + XOR swizzle [R16] -----------
// Same inner math; stage(t+1 -> buf^1) at iter top, ONE __syncthreads per
// iter whose implicit drain lands AFTER compute. 64KB LDS caps 2 blocks/CU --
// use ONLY where the grid is already <= 2 blocks/CU (out-GEMM: 512 blocks),
// so drain-hiding is free (R16/R17 A/B: out 35 -> ~19us; QKV would lose 16%).
template <bool BF16OUT>
__global__ __launch_bounds__(256) void gemm_bt64_db(const unsigned short* __restrict__ A,
                                                    const unsigned short* __restrict__ W,
                                                    void* __restrict__ Cout,
                                                    int M, int N, int K) {
    __shared__ unsigned short As[2][128 * 64];   // 2 x 16KB, swizzled layout
    __shared__ unsigned short Bs[2][128 * 64];
    const int tid = threadIdx.x;
    const int w = tid >> 6, lane = tid & 63;
    const int fr = lane & 15, fq = lane >> 4;
    const int m0 = blockIdx.y * 128, n0 = blockIdx.x * 128;
    const int wr = w >> 1, wc = w & 1;

    f32x4 acc[4][4];
#pragma unroll
    for (int a = 0; a < 4; a++)
#pragma unroll
        for (int b = 0; b < 4; b++) acc[a][b] = f32x4{0.f, 0.f, 0.f, 0.f};

    const int srow = lane >> 3;
    const int sce  = ((lane & 7) ^ (lane >> 3)) * 8;   // elems (inv-swizzle)

    auto stage = [&](int kt, int bufi) {
#pragma unroll
        for (int q = 0; q < 4; ++q) {
            const int i = w * 4 + q;               // 0..15
            const int r = i * 8 + srow;            // 0..127
            GLDS16(A + (size_t)(m0 + r) * K + kt + sce, &As[bufi][i * 512]);
            GLDS16(W + (size_t)(n0 + r) * K + kt + sce, &Bs[bufi][i * 512]);
        }
    };

    const int NT = K >> 6;   // 64-wide K-tiles
    int cur = 0;
    stage(0, 0);
    __syncthreads();         // compiler drains vmcnt before s_barrier

    for (int it = 0; it < NT; ++it) {
        if (it + 1 < NT) stage((it + 1) << 6, cur ^ 1);   // issue-early
#pragma unroll
        for (int kk = 0; kk < 2; ++kk) {
            bf16x8 af[4], bfr[4];
#pragma unroll
            for (int mi = 0; mi < 4; mi++) {
                const int row = wr * 64 + mi * 16 + fr;
                af[mi] = *reinterpret_cast<const bf16x8*>(
                    &As[cur][0] + row * 64 + ((((kk * 64 + fq * 16) ^ ((fr & 7) << 4))) >> 1));
            }
#pragma unroll
            for (int ni = 0; ni < 4; ni++) {
                const int row = wc * 64 + ni * 16 + fr;
                bfr[ni] = *reinterpret_cast<const bf16x8*>(
                    &Bs[cur][0] + row * 64 + ((((kk * 64 + fq * 16) ^ ((fr & 7) << 4))) >> 1));
            }
            __builtin_amdgcn_s_setprio(1);
#pragma unroll
            for (int mi = 0; mi < 4; mi++)
#pragma unroll
                for (int ni = 0; ni < 4; ni++)
                    acc[mi][ni] = MFMA(af[mi], bfr[ni], acc[mi][ni]);
            __builtin_amdgcn_s_setprio(0);
        }
        __syncthreads();     // drains staging (after compute) + orders reuse
        cur ^= 1;
    }

    // epilogue: C/D layout col=lane&15, row=(lane>>4)*4+reg  [verified m89/m91]
#pragma unroll
    for (int mi = 0; mi < 4; mi++) {
#pragma unroll
        for (int i = 0; i < 4; i++) {
            const int row = m0 + wr * 64 + mi * 16 + fq * 4 + i;
            const size_t base = (size_t)row * N + n0 + wc * 64 + fr;
#pragma unroll
            for (int ni = 0; ni < 4; ni++) {
                if (BF16OUT)
                    ((unsigned short*)Cout)[base + ni * 16] = f2bf(acc[mi][ni][i]);
                else
                    ((float*)Cout)[base + ni * 16] = acc[mi][ni][i];
            }
        }
    }
}

// ---------------- V transpose: qkv V-part [4096][2048] -> vT[2][2048][2048] --
__global__ __launch_bounds__(256) void transpose_v(const unsigned short* __restrict__ qkv,
                                                   unsigned short* __restrict__ vT) {
    __shared__ unsigned short t[32][33];
    const int b = blockIdx.z, ts = blockIdx.x, tu = blockIdx.y;
    const int i = threadIdx.x >> 5, j = threadIdx.x & 31;
#pragma unroll
    for (int ii = 0; ii < 4; ++ii) {
        const int row = i + ii * 8;
        t[row][j] = qkv[(size_t)(b * 2048 + ts * 32 + row) * 6144 + 4096 + tu * 32 + j];
    }
    __syncthreads();
#pragma unroll
    for (int ii = 0; ii < 4; ++ii) {
        const int row = i + ii * 8;
        vT[(size_t)(b * 2048 + tu * 32 + row) * 2048 + ts * 32 + j] = t[j][row];
    }
}

// ---------------- Flash attention, causal, block-cooperative, KVBLK=64 ------
// R10 configuration (best known): 512 blocks, each = one (b,h) x TWO 64-row
// q-supertiles {g=31-j, g=j} -> exactly 33 kv-iterations per block (perfect
// balance, 2 blocks/CU). Per kv-iter: stage K[64][128]+Vt[128][64] (32KB)
// into double-buffered LDS via global_load_lds (pre-swizzled source,
// XOR-swizzled reads, byte ^= ((row&7)<<4)). Fixed-reference exp2 softmax
// (no max-reduce), denominator on the MFMA pipe via ones-B.
#define SC2 (0.08838834764831845f * 1.4426950408889634f)  // SM_SCALE*log2(e)
#define MREF 20.0f

__global__ __launch_bounds__(256, 2) void attn_fwd(const unsigned short* __restrict__ qkv,
                                                   const unsigned short* __restrict__ vT,
                                                   unsigned short* __restrict__ ao) {
    __shared__ __align__(16) char Kt[2][16384];   // 64 rows x 256B
    __shared__ __align__(16) char Vt[2][16384];   // 128 rows x 128B
    __shared__ __align__(16) unsigned short Ps[4][16 * 72];  // 16 x 64, stride 72
    const int tid = threadIdx.x;
    const int w = tid >> 6, lane = tid & 63;
    const int fr = lane & 15, fq = lane >> 4;
    const int t = blockIdx.x;           // 512 blocks
    const int bh = t & 31;              // bh%8 ~ XCD id: 4 heads per XCD L2
    const int j = t >> 5;               // 0..15 -> pair {31-j, j}
    const int b = bh >> 4, h = bh & 15;

    const unsigned short* Qb = qkv + (size_t)b * 2048 * 6144 + h * 128;
    const unsigned short* Kb = qkv + (size_t)b * 2048 * 6144 + (16 + h) * 128;
    const unsigned short* Vb = vT + (size_t)bh * 128 * 2048;

    unsigned short* Pw = &Ps[w][0];
    const bf16x8 onesf = {0x3F80, 0x3F80, 0x3F80, 0x3F80, 0x3F80, 0x3F80, 0x3F80, 0x3F80};

    // staging: waves 0,1 -> K (16 x 1KB instr), waves 2,3 -> Vt (16 x 1KB).
    auto stage = [&](int kbs, int bufi) {
        const int k0s = kbs * 64;
        if (w < 2) {
#pragma unroll
            for (int q = 0; q < 8; ++q) {
                const int i = w * 8 + q;
                const int r = 4 * i + (lane >> 4);
                const int ce = ((((lane & 15) * 16) ^ ((r & 7) << 4))) >> 1;
                GLDS16(Kb + (size_t)(k0s + r) * 6144 + ce, &Kt[bufi][i * 1024]);
            }
        } else {
#pragma unroll
            for (int q = 0; q < 8; ++q) {
                const int i = (w - 2) * 8 + q;
                const int r = 8 * i + (lane >> 3);
                const int ce = ((lane & 7) ^ ((lane >> 3) & 7)) * 8;
                GLDS16(Vb + (size_t)r * 2048 + k0s + ce, &Vt[bufi][i * 1024]);
            }
        }
    };

#pragma unroll 1
    for (int seg = 0; seg < 2; ++seg) {
        const int g = seg ? j : 31 - j;   // heavy supertile first
        const int q0 = g * 64 + w * 16;
        const int nb = g + 1;

        bf16x8 qf[4];
        {
            const unsigned short* qr = Qb + (size_t)(q0 + fr) * 6144 + fq * 8;
#pragma unroll
            for (int c = 0; c < 4; c++) qf[c] = *reinterpret_cast<const bf16x8*>(qr + c * 32);
        }

        f32x4 acc[8];
#pragma unroll
        for (int f = 0; f < 8; f++) acc[f] = f32x4{0.f, 0.f, 0.f, 0.f};
        f32x4 accL = f32x4{0.f, 0.f, 0.f, 0.f};   // row-sum of P (denominator)

        int cur = 0;
        stage(0, 0);
        __syncthreads();

        for (int kb = 0; kb < nb; ++kb) {
            if (kb + 1 < nb) stage(kb + 1, cur ^ 1);
            const int k0 = kb * 64;
            const char* Kl = &Kt[cur][0];
            const char* Vl = &Vt[cur][0];

            // ---- QK^T: 4 16-col score tiles, two register-reusing halves ----
            f32x4 s[4];
#pragma unroll
            for (int th = 0; th < 2; ++th) {
                bf16x8 kf[2][4];
#pragma unroll
                for (int t2 = 0; t2 < 2; ++t2) {
                    const int tt = th * 2 + t2;
#pragma unroll
                    for (int c = 0; c < 4; ++c)
                        kf[t2][c] = *reinterpret_cast<const bf16x8*>(
                            Kl + (tt * 16 + fr) * 256 + ((c * 64 + fq * 16) ^ ((fr & 7) << 4)));
                }
                f32x4 a0 = f32x4{0.f, 0.f, 0.f, 0.f}, a1 = f32x4{0.f, 0.f, 0.f, 0.f};
                __builtin_amdgcn_s_setprio(1);
#pragma unroll
                for (int c = 0; c < 4; ++c) {
                    a0 = MFMA(qf[c], kf[0][c], a0);
                    a1 = MFMA(qf[c], kf[1][c], a1);
                }
                __builtin_amdgcn_s_setprio(0);
                s[th * 2] = a0; s[th * 2 + 1] = a1;
            }

            // ---- fixed-reference softmax: P = 2^(s*SC2 - MREF), no reduce ----
            const bool diag = (kb == nb - 1);   // wave-uniform
#pragma unroll
            for (int i = 0; i < 4; ++i) {
                const int qrow = q0 + fq * 4 + i;
#pragma unroll
                for (int tt = 0; tt < 4; ++tt) {
                    float a = __builtin_fmaf(s[tt][i], SC2, -MREF);
                    if (diag && (k0 + tt * 16 + fr > qrow)) a = -__builtin_inff();
                    Pw[(fq * 4 + i) * 72 + tt * 16 + fr] = f2bf(exp2f(a));
                }
            }

            // ---- PV + row-sum: two kv-halves of 32, register-reusing vf ----
#pragma unroll
            for (int h2 = 0; h2 < 2; ++h2) {
                bf16x8 pa = *reinterpret_cast<const bf16x8*>(Pw + fr * 72 + h2 * 32 + fq * 8);
                bf16x8 vf[8];
#pragma unroll
                for (int f = 0; f < 8; ++f)
                    vf[f] = *reinterpret_cast<const bf16x8*>(
                        Vl + (f * 16 + fr) * 128 + ((h2 * 64 + fq * 16) ^ ((fr & 7) << 4)));
                __builtin_amdgcn_s_setprio(1);
#pragma unroll
                for (int f = 0; f < 8; ++f) acc[f] = MFMA(pa, vf[f], acc[f]);
                accL = MFMA(pa, onesf, accL);   // denominator on the MFMA pipe
                __builtin_amdgcn_s_setprio(0);
            }

            __syncthreads();
            cur ^= 1;
        }

        // epilogue: normalize (reciprocal-multiply) and store bf16 [4096][2048]
        float inv[4];
#pragma unroll
        for (int i = 0; i < 4; ++i) inv[i] = 1.0f / accL[i];
#pragma unroll
        for (int f = 0; f < 8; f++) {
#pragma unroll
            for (int i = 0; i < 4; i++) {
                const int qrow = q0 + fq * 4 + i;
                const float o = acc[f][i] * inv[i];
                ao[(size_t)(b * 2048 + qrow) * 2048 + h * 128 + f * 16 + fr] = f2bf(o);
            }
        }
        // all waves passed the loop's final barrier; epilogue touches no LDS,
        // so seg1's stage(0,0) can safely overwrite buffers.
    }
}

// ---------------------------------------------------------------------------
extern "C" void kernel_launch(void* const* d_in, const int* in_sizes, int n_in,
                              void* d_out, int out_size, void* d_ws, size_t ws_size,
                              hipStream_t stream) {
    const float* x    = (const float*)d_in[0];
    const float* Wqkv = (const float*)d_in[1];
    const float* Wout = (const float*)d_in[2];
    float* out = (float*)d_out;

    // Workspace layout (96 MB), regions reused across phases:
    //   [0,16M):   xb (bf16 x), later reused as attnb
    //   [16M,40M): wqkvb (24M), later reused as vT (16M)
    //   [40M,48M): woutb
    //   [48M,96M): qkvb (bf16 [4096][6144])
    char* ws = (char*)d_ws;
    unsigned short* xb    = (unsigned short*)(ws);
    unsigned short* wqkvb = (unsigned short*)(ws + (size_t)(16 << 20));
    unsigned short* woutb = (unsigned short*)(ws + (size_t)(40 << 20));
    unsigned short* qkvb  = (unsigned short*)(ws + (size_t)(48 << 20));
    unsigned short* vTb   = (unsigned short*)(ws + (size_t)(16 << 20)); // over wqkvb
    unsigned short* attnb = (unsigned short*)(ws);                      // over xb

    // fused fp32->bf16 convert of x, W_qkv, W_out (one dispatch)
    cvt3_f32_bf16<<<24576, 256, 0, stream>>>(x, Wqkv, Wout, xb, wqkvb, woutb);

    // qkv = x @ W_qkv^T : M=4096, N=6144, K=2048, bf16 out
    // single-buffer BK=64 (1536 blocks -> occupancy-bound: sb wins, R16 A/B)
    gemm_bt64<true><<<dim3(48, 32), 256, 0, stream>>>(xb, wqkvb, qkvb, 4096, 6144, 2048);

    // vT[b][h*128+dk][s] = V[b][s][h*128+dk]  (wqkvb dead after the GEMM)
    transpose_v<<<dim3(64, 64, 2), 256, 0, stream>>>(qkvb, vTb);

    // causal flash attention -> attnb (bf16 [4096][2048])  (xb dead now)
    attn_fwd<<<512, 256, 0, stream>>>(qkvb, vTb, attnb);

    // out = attnb @ W_out^T : M=4096, N=2048, K=2048, fp32 out
    // double-buffer BK=64 (512 blocks = 2/CU by grid -> dbuf free, R16 A/B)
    gemm_bt64_db<false><<<dim3(16, 32), 256, 0, stream>>>(attnb, woutb, out, 4096, 2048, 2048);
}